// Round 2
// baseline (27700.793 us; speedup 1.0000x reference)
//
#include <hip/hip_runtime.h>

namespace {

constexpr int B = 128;
constexpr int T = 1024;
constexpr int DIN = 48;
constexpr int H = 256;
constexpr int G = 4 * H;          // 1024 gate rows per direction
constexpr int NTHREADS = 512;

constexpr size_t BH          = (size_t)B * H;                        // 32768
constexpr size_t WT_FLOATS   = 4 * 256 * 1024 + 2 * 48 * 1024 + 2 * 512 * 1024; // 2,195,456
constexpr size_t STATE_FLOATS= 12 * BH;                              // 393,216
constexpr size_t O0_ELEMS    = (size_t)B * T * 512;                  // 67,108,864

__device__ __forceinline__ float sigmoidf_(float x) {
    float z = __expf(-fabsf(x));
    float s = 1.0f / (1.0f + z);
    return x >= 0.0f ? s : 1.0f - s;
}
__device__ __forceinline__ float tanhf_(float x) {
    float z = __expf(-2.0f * fabsf(x));
    float tp = (1.0f - z) / (1.0f + z);
    return x >= 0.0f ? tp : -tp;
}
__device__ __forceinline__ float bf2f(unsigned short s) {
    union { unsigned int u; float f; } v; v.u = ((unsigned int)s) << 16; return v.f;
}
__device__ __forceinline__ unsigned short f2bf(float f) {
    union { float f; unsigned int u; } v; v.f = f;
    unsigned int u = v.u;
    return (unsigned short)((u + 0x7FFFu + ((u >> 16) & 1u)) >> 16);  // RNE
}

__global__ void zero_f(float* __restrict__ p, int n) {
    int i = blockIdx.x * blockDim.x + threadIdx.x;
    if (i < n) p[i] = 0.0f;
}

// dst[k][r] = src[r][k], src is [1024][K]; output-coalesced
__global__ void transpose_w(const float* __restrict__ src, float* __restrict__ dst, int K) {
    int idx = blockIdx.x * blockDim.x + threadIdx.x;
    if (idx >= K * 1024) return;
    int r = idx & 1023;
    int k = idx >> 10;
    dst[idx] = src[r * K + k];
}

// One recurrence step for BOTH directions of one layer.
// Grid: 256 blocks = 2 dirs x 16 batch-tiles(8) x 8 channel-tiles(32).
// Block: 512 threads = 16 k-slices x 32 row-quads.
// h is ping-pong double-buffered across steps (other channel-tiles of the same
// batch read the full h row, so in-place update would race). c is block-exclusive.
// XT = element type of xin (float or bf16-ushort); OT = element type of oout.
template<int INP, int XKK, int XSL, int XPB, int KSMAX, bool WRITE_OUT, typename XT, typename OT>
__global__ __launch_bounds__(NTHREADS)
void lstm_step(int s,
               const XT* __restrict__ xin, int xstride,   // row (b,t) at ((b*T)+t)*xstride
               const float* __restrict__ wih_t_f, const float* __restrict__ wih_t_b, // [INP][1024]
               const float* __restrict__ whh_t_f, const float* __restrict__ whh_t_b, // [256][1024]
               const float* __restrict__ bih_f,  const float* __restrict__ bhh_f,
               const float* __restrict__ bih_b,  const float* __restrict__ bhh_b,
               const float* __restrict__ h_in,   // [2][B][H]
               float* __restrict__ h_out,        // [2][B][H]
               float* __restrict__ c_st,         // [2][B][H]
               OT* __restrict__ oout,            // [B][T][512] or nullptr
               const int* __restrict__ lengths)
{
    const int bx  = blockIdx.x;
    const int d   = bx >> 7;                // 0 fwd, 1 bwd
    const int rem = bx & 127;
    const int b0  = (rem >> 3) * 8;
    const int c0  = (rem & 7) * 32;
    const int tid = threadIdx.x;
    const int ks  = tid & 15;               // k-slice
    const int rq  = tid >> 4;               // row-quad 0..31

    const int t = d ? (T - 1 - s) : s;

    const float* wih_t = d ? wih_t_b : wih_t_f;
    const float* whh_t = d ? whh_t_b : whh_t_f;
    const float* bih   = d ? bih_b : bih_f;
    const float* bhh   = d ? bhh_b : bhh_f;
    const float* hrow_in  = h_in  + d * (B * H);
    float*       hrow_out = h_out + d * (B * H);
    float*       crow     = c_st  + d * (B * H);

    // skewed LDS layouts: slice stride padded so the 16 ks-groups land on
    // distinct bank quads (<=2-way conflicts, free per m136).
    __shared__ float4 lds_x4[8 * XPB];
    __shared__ float4 lds_h4[8 * 80];       // 16 slices x 5 f4 per batch
    __shared__ float  lds_g[128 * 9];       // gates [r_local][b], pad 9 vs bank stride

    // ---- stage x tile ----
    {
        const int nchunk = INP / 4;
        for (int i = tid; i < 8 * nchunk; i += NTHREADS) {
            int b, k4;
            if constexpr (INP == 48) { b = i / 12; k4 = i - b * 12; }
            else                     { b = i >> 7; k4 = i & 127; }
            const XT* src = xin + ((size_t)(b0 + b) * T + t) * xstride + k4 * 4;
            float4 v;
            if constexpr (sizeof(XT) == 4) {
                v = *(const float4*)src;
            } else {
                ushort4 uv = *(const ushort4*)src;
                v = make_float4(bf2f(uv.x), bf2f(uv.y), bf2f(uv.z), bf2f(uv.w));
            }
            int slot;
            if constexpr (INP == 48) slot = b * XPB + k4 * XSL;                      // XKK=1: k4==ks
            else                     slot = b * XPB + (k4 >> 3) * XSL + (k4 & 7);    // XKK=8
            lds_x4[slot] = v;
        }
    }
    // ---- stage h tile ----
    for (int i = tid; i < 8 * 64; i += NTHREADS) {
        int b = i >> 6, k4 = i & 63;
        float4 v = *(const float4*)(hrow_in + (b0 + b) * H + k4 * 4);
        lds_h4[b * 80 + (k4 >> 2) * 5 + (k4 & 3)] = v;
    }
    __syncthreads();

    const int rbase = rq * 4;               // local row 0..124 (gate-major: 4 gates x 32 ch)
    const int gate  = rbase >> 5;
    const int chl4  = rbase & 31;
    const int grow0 = gate * 256 + c0 + chl4;   // global gate-row of acc[0] (4-aligned)

    float acc[4][8];
    #pragma unroll
    for (int i = 0; i < 4; i++)
        #pragma unroll
        for (int b = 0; b < 8; b++) acc[i][b] = 0.0f;

    // ---- x part: W_t rows contiguous -> float4 over 4 consecutive gate-rows ----
    if (ks < KSMAX) {
        #pragma unroll
        for (int kk = 0; kk < XKK; kk++) {
            float4 xv[8];
            #pragma unroll
            for (int b = 0; b < 8; b++) xv[b] = lds_x4[b * XPB + ks * XSL + kk];
            const int kbase = (ks * XKK + kk) * 4;
            #pragma unroll
            for (int j = 0; j < 4; j++) {
                float4 w4 = *(const float4*)(wih_t + (kbase + j) * G + grow0);
                #pragma unroll
                for (int b = 0; b < 8; b++) {
                    float xs = (j == 0) ? xv[b].x : (j == 1) ? xv[b].y : (j == 2) ? xv[b].z : xv[b].w;
                    acc[0][b] = fmaf(w4.x, xs, acc[0][b]);
                    acc[1][b] = fmaf(w4.y, xs, acc[1][b]);
                    acc[2][b] = fmaf(w4.z, xs, acc[2][b]);
                    acc[3][b] = fmaf(w4.w, xs, acc[3][b]);
                }
            }
        }
    }

    // ---- h part: K=256, 16 floats per ks ----
    #pragma unroll
    for (int kk = 0; kk < 4; kk++) {
        float4 hv[8];
        #pragma unroll
        for (int b = 0; b < 8; b++) hv[b] = lds_h4[b * 80 + ks * 5 + kk];
        const int kbase = (ks * 4 + kk) * 4;
        #pragma unroll
        for (int j = 0; j < 4; j++) {
            float4 w4 = *(const float4*)(whh_t + (kbase + j) * G + grow0);
            #pragma unroll
            for (int b = 0; b < 8; b++) {
                float xs = (j == 0) ? hv[b].x : (j == 1) ? hv[b].y : (j == 2) ? hv[b].z : hv[b].w;
                acc[0][b] = fmaf(w4.x, xs, acc[0][b]);
                acc[1][b] = fmaf(w4.y, xs, acc[1][b]);
                acc[2][b] = fmaf(w4.z, xs, acc[2][b]);
                acc[3][b] = fmaf(w4.w, xs, acc[3][b]);
            }
        }
    }

    // ---- reduce over the 16 k-slices (lane bits 0..3) ----
    #pragma unroll
    for (int i = 0; i < 4; i++)
        #pragma unroll
        for (int b = 0; b < 8; b++) {
            float v = acc[i][b];
            v += __shfl_xor(v, 1, 64);
            v += __shfl_xor(v, 2, 64);
            v += __shfl_xor(v, 4, 64);
            v += __shfl_xor(v, 8, 64);
            acc[i][b] = v;
        }
    if (ks == 0) {
        #pragma unroll
        for (int i = 0; i < 4; i++)
            #pragma unroll
            for (int b = 0; b < 8; b++)
                lds_g[(rbase + i) * 9 + b] = acc[i][b];
    }
    __syncthreads();

    // ---- elementwise gate math: 256 (channel, batch) pairs ----
    if (tid < 256) {
        const int chl = tid & 31;
        const int b   = tid >> 5;
        const int gch = c0 + chl;
        float gi = lds_g[(0 * 32 + chl) * 9 + b] + bih[0 * 256 + gch] + bhh[0 * 256 + gch];
        float gf = lds_g[(1 * 32 + chl) * 9 + b] + bih[1 * 256 + gch] + bhh[1 * 256 + gch];
        float gg = lds_g[(2 * 32 + chl) * 9 + b] + bih[2 * 256 + gch] + bhh[2 * 256 + gch];
        float go = lds_g[(3 * 32 + chl) * 9 + b] + bih[3 * 256 + gch] + bhh[3 * 256 + gch];
        float iv = sigmoidf_(gi);
        float fv = sigmoidf_(gf);
        float gv = tanhf_(gg);
        float ov = sigmoidf_(go);
        const int sidx = (b0 + b) * H + gch;
        float c_old = crow[sidx];
        float h_old = hrow_in[sidx];
        float c_new = fv * c_old + iv * gv;
        float h_new = ov * tanhf_(c_new);
        bool valid = t < lengths[b0 + b];
        if (valid) crow[sidx] = c_new;
        hrow_out[sidx] = valid ? h_new : h_old;   // propagate state through the ping-pong
        if constexpr (WRITE_OUT) {
            float hv = valid ? h_new : 0.0f;
            size_t oidx = ((size_t)(b0 + b) * T + t) * 512 + d * 256 + gch;
            if constexpr (sizeof(OT) == 4) oout[oidx] = hv;
            else                           oout[oidx] = f2bf(hv);
        }
    }
}

__global__ __launch_bounds__(256)
void fc_head(const float* __restrict__ h1,   // [2][B][H] final layer-1 h (parity 0)
             const float* __restrict__ fc1w, const float* __restrict__ fc1b,
             const float* __restrict__ fc2w, const float* __restrict__ fc2b,
             float* __restrict__ out)
{
    int b = blockIdx.x;
    int tid = threadIdx.x;
    __shared__ float hid[512];
    __shared__ float red[4];
    hid[tid]       = h1[b * H + tid];
    hid[256 + tid] = h1[(size_t)B * H + b * H + tid];
    __syncthreads();
    float a = fc1b[tid];
    const float4* w4 = (const float4*)(fc1w + tid * 512);
    const float4* h4 = (const float4*)hid;
    #pragma unroll 4
    for (int k = 0; k < 128; k++) {
        float4 w = w4[k], h = h4[k];
        a = fmaf(w.x, h.x, a); a = fmaf(w.y, h.y, a);
        a = fmaf(w.z, h.z, a); a = fmaf(w.w, h.w, a);
    }
    float r = fmaxf(a, 0.0f);
    float v = r * fc2w[tid];
    #pragma unroll
    for (int off = 32; off > 0; off >>= 1) v += __shfl_down(v, off, 64);
    if ((tid & 63) == 0) red[tid >> 6] = v;
    __syncthreads();
    if (tid == 0) out[b] = red[0] + red[1] + red[2] + red[3] + fc2b[0];
}

} // namespace

extern "C" void kernel_launch(void* const* d_in, const int* in_sizes, int n_in,
                              void* d_out, int out_size, void* d_ws, size_t ws_size,
                              hipStream_t stream)
{
    const float* x        = (const float*)d_in[0];
    const int*   lengths  = (const int*)d_in[1];
    const float* w_ih_l0f = (const float*)d_in[2];
    const float* w_hh_l0f = (const float*)d_in[3];
    const float* b_ih_l0f = (const float*)d_in[4];
    const float* b_hh_l0f = (const float*)d_in[5];
    const float* w_ih_l0b = (const float*)d_in[6];
    const float* w_hh_l0b = (const float*)d_in[7];
    const float* b_ih_l0b = (const float*)d_in[8];
    const float* b_hh_l0b = (const float*)d_in[9];
    const float* w_ih_l1f = (const float*)d_in[10];
    const float* w_hh_l1f = (const float*)d_in[11];
    const float* b_ih_l1f = (const float*)d_in[12];
    const float* b_hh_l1f = (const float*)d_in[13];
    const float* w_ih_l1b = (const float*)d_in[14];
    const float* w_hh_l1b = (const float*)d_in[15];
    const float* b_ih_l1b = (const float*)d_in[16];
    const float* b_hh_l1b = (const float*)d_in[17];
    const float* fc1w     = (const float*)d_in[18];
    const float* fc1b     = (const float*)d_in[19];
    const float* fc2w     = (const float*)d_in[20];
    const float* fc2b     = (const float*)d_in[21];

    float* ws = (float*)d_ws;

    // ---- workspace layout: [weights | state | O0] ----
    float* whh_t_l0f = ws;
    float* whh_t_l0b = whh_t_l0f + 256 * 1024;
    float* whh_t_l1f = whh_t_l0b + 256 * 1024;
    float* whh_t_l1b = whh_t_l1f + 256 * 1024;
    float* wih_t_l0f = whh_t_l1b + 256 * 1024;  // [48][1024]
    float* wih_t_l0b = wih_t_l0f + 48 * 1024;
    float* wih_t_l1f = wih_t_l0b + 48 * 1024;   // [512][1024]
    float* wih_t_l1b = wih_t_l1f + 512 * 1024;

    float* state = ws + WT_FLOATS;
    float* h_l0 = state;                        // [2 parity][2 dir][B][H]
    float* h_l1 = h_l0 + 4 * BH;
    float* c_l0 = h_l1 + 4 * BH;                // [2 dir][B][H]
    float* c_l1 = c_l0 + 2 * BH;
    void*  O0   = (void*)(state + STATE_FLOATS);

    // ws_size is invariant across calls -> this branch is deterministic.
    const size_t base_bytes = (WT_FLOATS + STATE_FLOATS) * sizeof(float);
    const bool o0_f32 = ws_size >= base_bytes + O0_ELEMS * sizeof(float);

    // zero h (both parities) and c for both layers (ws is poisoned 0xAA each call)
    zero_f<<<(int)((STATE_FLOATS + 255) / 256), 256, 0, stream>>>(state, (int)STATE_FLOATS);

    // weight transposes (per call; cheap, graph-captured)
    transpose_w<<<256 * 1024 / 256, 256, 0, stream>>>(w_hh_l0f, whh_t_l0f, 256);
    transpose_w<<<256 * 1024 / 256, 256, 0, stream>>>(w_hh_l0b, whh_t_l0b, 256);
    transpose_w<<<256 * 1024 / 256, 256, 0, stream>>>(w_hh_l1f, whh_t_l1f, 256);
    transpose_w<<<256 * 1024 / 256, 256, 0, stream>>>(w_hh_l1b, whh_t_l1b, 256);
    transpose_w<<<48 * 1024 / 256, 256, 0, stream>>>(w_ih_l0f, wih_t_l0f, 48);
    transpose_w<<<48 * 1024 / 256, 256, 0, stream>>>(w_ih_l0b, wih_t_l0b, 48);
    transpose_w<<<512 * 1024 / 256, 256, 0, stream>>>(w_ih_l1f, wih_t_l1f, 512);
    transpose_w<<<512 * 1024 / 256, 256, 0, stream>>>(w_ih_l1b, wih_t_l1b, 512);

    if (o0_f32) {
        float* O0f = (float*)O0;
        for (int s = 0; s < T; s++) {
            const float* hin = h_l0 + (size_t)(s & 1) * 2 * BH;
            float* hout      = h_l0 + (size_t)((s & 1) ^ 1) * 2 * BH;
            lstm_step<48, 1, 3, 48, 12, true, float, float><<<256, NTHREADS, 0, stream>>>(
                s, x, DIN,
                wih_t_l0f, wih_t_l0b, whh_t_l0f, whh_t_l0b,
                b_ih_l0f, b_hh_l0f, b_ih_l0b, b_hh_l0b,
                hin, hout, c_l0, O0f, lengths);
        }
        for (int s = 0; s < T; s++) {
            const float* hin = h_l1 + (size_t)(s & 1) * 2 * BH;
            float* hout      = h_l1 + (size_t)((s & 1) ^ 1) * 2 * BH;
            lstm_step<512, 8, 9, 144, 16, false, float, float><<<256, NTHREADS, 0, stream>>>(
                s, O0f, 512,
                wih_t_l1f, wih_t_l1b, whh_t_l1f, whh_t_l1b,
                b_ih_l1f, b_hh_l1f, b_ih_l1b, b_hh_l1b,
                hin, hout, c_l1, (float*)nullptr, lengths);
        }
    } else {
        unsigned short* O0h = (unsigned short*)O0;
        for (int s = 0; s < T; s++) {
            const float* hin = h_l0 + (size_t)(s & 1) * 2 * BH;
            float* hout      = h_l0 + (size_t)((s & 1) ^ 1) * 2 * BH;
            lstm_step<48, 1, 3, 48, 12, true, float, unsigned short><<<256, NTHREADS, 0, stream>>>(
                s, x, DIN,
                wih_t_l0f, wih_t_l0b, whh_t_l0f, whh_t_l0b,
                b_ih_l0f, b_hh_l0f, b_ih_l0b, b_hh_l0b,
                hin, hout, c_l0, O0h, lengths);
        }
        for (int s = 0; s < T; s++) {
            const float* hin = h_l1 + (size_t)(s & 1) * 2 * BH;
            float* hout      = h_l1 + (size_t)((s & 1) ^ 1) * 2 * BH;
            lstm_step<512, 8, 9, 144, 16, false, unsigned short, float><<<256, NTHREADS, 0, stream>>>(
                s, O0h, 512,
                wih_t_l1f, wih_t_l1b, whh_t_l1f, whh_t_l1b,
                b_ih_l1f, b_hh_l1f, b_ih_l1b, b_hh_l1b,
                hin, hout, c_l1, (float*)nullptr, lengths);
        }
    }
    // FC head: T even -> final h lives at parity 0
    fc_head<<<B, 256, 0, stream>>>(h_l1, fc1w, fc1b, fc2w, fc2b, (float*)d_out);
}